// Round 5
// baseline (81.090 us; speedup 1.0000x reference)
//
#include <hip/hip_runtime.h>

// LIF integrate-fire-reset over the time axis.
// x: [B=64, C=2048, T=256] f32 row-major -> 131072 rows of 256 contiguous floats.
// u_t = TAU*u_{t-1}*(1-s_{t-1}) + x_t ; s_t = (u_t > VTH).
//
// R2 structure (measured best 44.8us, 1x traffic, 0 bank conflicts):
//   256-thread blocks, 512 blocks (8 waves/CU), float4 loads staged to
//   double-buffered stride-36 LDS, lgkmcnt-only barrier per chunk (vmcnt never
//   drained), spike masks exchanged via wave shuffle, nontemporal float4 stores.
//
// R5 change: depth-2 register prefetch with SCRATCH-PROOF indexing. R3/R4's
// p[2][8] indexed by (k&1) went to scratch (VGPR stuck at 88, WRITE_SIZE
// doubled to 261MB = spill traffic). Here: NAMED pA/pB arrays, two chunks per
// loop iteration, every array subscript is a literal inside #pragma unroll 8 --
// the compiler can always register-allocate them (rule #20).

#define T_LEN 256
#define TQ 64              // float4 per row
#define RPB 256            // rows per block == threads per block
#define XS_STRIDE 36       // LDS words per row (32 + 4 pad)

#define TAU 0.25f
#define VTH 0.5f

typedef float f32x4 __attribute__((ext_vector_type(4)));

__global__ __launch_bounds__(RPB, 2)
void lif_kernel(const float* __restrict__ x, float* __restrict__ out) {
    __shared__ __align__(16) float xs[2][RPB * XS_STRIDE];  // 2 x 36864 B

    const int tid  = threadIdx.x;
    const int lane = tid & 63;
    const int wv   = tid >> 6;
    const long rbase = (long)blockIdx.x * RPB;

    const float4* __restrict__ x4 = reinterpret_cast<const float4*>(x);

    const int qs = tid & 7;   // float4 slot this thread stages
    const int rs = tid >> 3;  // base staging row (stride 32 per i)

    // ---- prologue: prefetch chunks 0 (pA) and 1 (pB) ----
    float4 pA[8], pB[8];
    #pragma unroll 8
    for (int i = 0; i < 8; ++i)
        pA[i] = x4[(rbase + rs + i * 32) * TQ + 0 * 8 + qs];
    #pragma unroll 8
    for (int i = 0; i < 8; ++i)
        pB[i] = x4[(rbase + rs + i * 32) * TQ + 1 * 8 + qs];

    float u = 0.0f;
    bool sprev = false;

    // One half-phase: stage chunk KC from regs P into LDS buffer BUF, prefetch
    // chunk KP into P, run 32 LIF steps, store spikes. All P subscripts literal.
#define HALF(P, BUF, KC, KP)                                                     \
    {                                                                            \
        _Pragma("unroll 8")                                                      \
        for (int i = 0; i < 8; ++i)                                              \
            *reinterpret_cast<float4*>(&BUF[(rs + i * 32) * XS_STRIDE + 4 * qs]) = P[i]; \
        asm volatile("s_waitcnt lgkmcnt(0)" ::: "memory");                       \
        __builtin_amdgcn_s_barrier();                                            \
        if ((KP) < 8) {                                                          \
            _Pragma("unroll 8")                                                  \
            for (int i = 0; i < 8; ++i)                                          \
                P[i] = x4[(rbase + rs + i * 32) * TQ + (KP) * 8 + qs];           \
        }                                                                        \
        float4 v[8];                                                             \
        _Pragma("unroll 8")                                                      \
        for (int i = 0; i < 8; ++i)                                              \
            v[i] = *reinterpret_cast<const float4*>(&BUF[tid * XS_STRIDE + 4 * i]); \
        unsigned int m = 0;                                                      \
        _Pragma("unroll 8")                                                      \
        for (int i = 0; i < 8; ++i) {                                            \
            float e[4] = { v[i].x, v[i].y, v[i].z, v[i].w };                     \
            _Pragma("unroll 4")                                                  \
            for (int j = 0; j < 4; ++j) {                                        \
                float um = sprev ? 0.0f : __fmul_rn(TAU, u);                     \
                u = __fadd_rn(um, e[j]);                                         \
                sprev = u > VTH;                                                 \
                m |= (sprev ? 1u : 0u) << (i * 4 + j);                           \
            }                                                                    \
        }                                                                        \
        _Pragma("unroll 8")                                                      \
        for (int i = 0; i < 8; ++i) {                                            \
            int rowl = i * 8 + (lane >> 3);                                      \
            unsigned int mr = (unsigned int)__shfl((int)m, rowl, 64);            \
            int toff = 4 * (lane & 7);                                           \
            f32x4 o;                                                             \
            o[0] = ((mr >> (toff + 0)) & 1u) ? 1.0f : 0.0f;                      \
            o[1] = ((mr >> (toff + 1)) & 1u) ? 1.0f : 0.0f;                      \
            o[2] = ((mr >> (toff + 2)) & 1u) ? 1.0f : 0.0f;                      \
            o[3] = ((mr >> (toff + 3)) & 1u) ? 1.0f : 0.0f;                      \
            long gq = (rbase + wv * 64 + rowl) * (long)TQ + (KC) * 8 + (lane & 7); \
            __builtin_nontemporal_store(o, reinterpret_cast<f32x4*>(out) + gq);  \
        }                                                                        \
    }

    for (int kk = 0; kk < 4; ++kk) {
        const int k0 = 2 * kk;
        // Even chunk: LDS buffer 0, regs pA; prefetch chunk k0+2 into pA.
        HALF(pA, (xs[0]), k0, k0 + 2)
        // Odd chunk: LDS buffer 1, regs pB; prefetch chunk k0+3 into pB.
        HALF(pB, (xs[1]), k0 + 1, k0 + 3)
        // Barrier-hazard note: each buffer's ds_reads are drained (lgkmcnt(0))
        // before the NEXT barrier any wave can pass, and each buffer is only
        // re-staged after one further barrier -- same discipline as R2.
    }
#undef HALF
}

extern "C" void kernel_launch(void* const* d_in, const int* in_sizes, int n_in,
                              void* d_out, int out_size, void* d_ws, size_t ws_size,
                              hipStream_t stream) {
    const float* x = (const float*)d_in[0];
    float* out = (float*)d_out;
    const int total = in_sizes[0];      // 64*2048*256
    const int nrows = total / T_LEN;    // 131072
    const int blocks = nrows / RPB;     // 512
    lif_kernel<<<blocks, RPB, 0, stream>>>(x, out);
}

// Round 6
// 44.847 us; speedup vs baseline: 1.8081x; 1.8081x over previous
//
#include <hip/hip_runtime.h>

// LIF integrate-fire-reset over the time axis.
// x: [B=64, C=2048, T=256] f32 row-major -> 131072 rows of 256 contiguous floats.
// u_t = TAU*u_{t-1}*(1-s_{t-1}) + x_t ; s_t = (u_t > VTH).
//
// EXACT revert to the measured-best R2 kernel (44.8us, FETCH 65MB, WRITE 131MB,
// 0 bank conflicts, VGPR 88). Structure:
//   - 256-thread blocks, 512 blocks (2 blocks/CU, 8 waves/CU),
//   - coalesced float4 global loads staged to double-buffered LDS (stride-36
//     rows: conflict-free b128 writes and reads),
//   - depth-1 register prefetch issued right after the barrier (chunk phase
//     ~13K cycles >> 900cy HBM latency, so depth-1 slack is sufficient;
//     every depth-2 variant tried (R3/R4/R5) spilled and doubled WRITE_SIZE),
//   - lgkmcnt-only barrier (raw s_barrier; vmcnt never drained -> prefetch
//     loads and output stores stay in flight across chunks),
//   - spikes packed to 32-bit masks, exchanged wave-locally via __shfl,
//     expanded to coalesced NONTEMPORAL float4 stores.
// Roofline position: 268 MB compulsory CU-side traffic / 44.8us = 5.98 TB/s =
// 96% of the measured 6.29 TB/s achievable aggregate -> at the memory roofline.

#define T_LEN 256
#define TQ 64              // float4 per row
#define NCH 8              // 8 chunks of 32 timesteps
#define RPB 256            // rows per block == threads per block
#define XS_STRIDE 36       // LDS words per row (32 + 4 pad)

#define TAU 0.25f
#define VTH 0.5f

typedef float f32x4 __attribute__((ext_vector_type(4)));

__global__ __launch_bounds__(RPB, 2)
void lif_kernel(const float* __restrict__ x, float* __restrict__ out) {
    __shared__ __align__(16) float xs[2][RPB * XS_STRIDE];  // 2 x 36864 B

    const int tid  = threadIdx.x;
    const int lane = tid & 63;
    const int wv   = tid >> 6;
    const long rbase = (long)blockIdx.x * RPB;

    const float4* __restrict__ x4 = reinterpret_cast<const float4*>(x);
    float* __restrict__ outp = out;

    const int qs = tid & 7;   // float4 slot this thread stages
    const int rs = tid >> 3;  // base staging row (stride 32 per i)

    // ---- prologue: prefetch chunk 0 into registers ----
    float4 p[8];
    #pragma unroll
    for (int i = 0; i < 8; ++i)
        p[i] = x4[(rbase + rs + i * 32) * TQ + qs];

    float u = 0.0f;
    bool sprev = false;

    #pragma unroll
    for (int k = 0; k < NCH; ++k) {
        float* buf = xs[k & 1];

        // ---- stage chunk k: regs -> LDS (b128, conflict-free) ----
        #pragma unroll
        for (int i = 0; i < 8; ++i)
            *reinterpret_cast<float4*>(&buf[(rs + i * 32) * XS_STRIDE + 4 * qs]) = p[i];

        // lgkm-only barrier: do NOT drain vmcnt (stores/prefetch stay in flight)
        asm volatile("s_waitcnt lgkmcnt(0)" ::: "memory");
        __builtin_amdgcn_s_barrier();

        // ---- prefetch chunk k+1 (in flight during the serial compute) ----
        if (k + 1 < NCH) {
            #pragma unroll
            for (int i = 0; i < 8; ++i)
                p[i] = x4[(rbase + rs + i * 32) * TQ + (k + 1) * 8 + qs];
        }

        // ---- read own row from LDS ----
        float4 v[8];
        #pragma unroll
        for (int i = 0; i < 8; ++i)
            v[i] = *reinterpret_cast<const float4*>(&buf[tid * XS_STRIDE + 4 * i]);

        // ---- 32 sequential LIF steps, bit-exact vs reference ----
        unsigned int m = 0;
        #pragma unroll
        for (int i = 0; i < 8; ++i) {
            float e[4] = { v[i].x, v[i].y, v[i].z, v[i].w };
            #pragma unroll
            for (int j = 0; j < 4; ++j) {
                float um = sprev ? 0.0f : __fmul_rn(TAU, u);
                u = __fadd_rn(um, e[j]);
                sprev = u > VTH;
                m |= (sprev ? 1u : 0u) << (i * 4 + j);
            }
        }

        // ---- wave-local mask exchange + nontemporal coalesced stores ----
        #pragma unroll
        for (int i = 0; i < 8; ++i) {
            int rowl = i * 8 + (lane >> 3);                       // row within wave tile
            unsigned int mr = (unsigned int)__shfl((int)m, rowl, 64);
            int toff = 4 * (lane & 7);
            f32x4 o;
            o[0] = ((mr >> (toff + 0)) & 1u) ? 1.0f : 0.0f;
            o[1] = ((mr >> (toff + 1)) & 1u) ? 1.0f : 0.0f;
            o[2] = ((mr >> (toff + 2)) & 1u) ? 1.0f : 0.0f;
            o[3] = ((mr >> (toff + 3)) & 1u) ? 1.0f : 0.0f;
            long gq = (rbase + wv * 64 + rowl) * (long)TQ + k * 8 + (lane & 7);
            __builtin_nontemporal_store(o, reinterpret_cast<f32x4*>(outp) + gq);
        }
        // Next iteration writes the OTHER LDS buffer; its prior readers finished
        // before the barrier above (lgkmcnt(0) precedes s_barrier). One barrier
        // per chunk is sufficient.
    }
}

extern "C" void kernel_launch(void* const* d_in, const int* in_sizes, int n_in,
                              void* d_out, int out_size, void* d_ws, size_t ws_size,
                              hipStream_t stream) {
    const float* x = (const float*)d_in[0];
    float* out = (float*)d_out;
    const int total = in_sizes[0];      // 64*2048*256
    const int nrows = total / T_LEN;    // 131072
    const int blocks = nrows / RPB;     // 512
    lif_kernel<<<blocks, RPB, 0, stream>>>(x, out);
}